// Round 1
// baseline (133.248 us; speedup 1.0000x reference)
//
#include <hip/hip_runtime.h>
#include <hip/hip_bf16.h>

#define NNODES 20000
#define NE_RAW 200000
#define NE_TOT 220000
#define MAX1   256
#define MAX2   2048
#define MAXE1  4096
#define MAXE2  256
#define FIN    1280
#define FH     1024
#define HC     256
#define NHEAD  4
#define C2     128
#define CAPE   512
#define K3_GEMM_BLOCKS 264

__device__ __forceinline__ float lrelu(float x){ return x >= 0.f ? x : 0.2f * x; }

__device__ __forceinline__ float blockSum(float v, float* red4){
  #pragma unroll
  for (int o = 32; o; o >>= 1) v += __shfl_xor(v, o, 64);
  int t = threadIdx.x;
  __syncthreads();
  if ((t & 63) == 0) red4[t >> 6] = v;
  __syncthreads();
  return red4[0] + red4[1] + red4[2] + red4[3];
}

// K0: reset slot maps + counters (hh zeroed via hipMemsetAsync)
__global__ void k_init(int* cnt, int* slot1, int* slot2){
  int i = blockIdx.x * 256 + threadIdx.x;
  if (i < NNODES){ slot1[i] = -1; slot2[i] = -1; }
  if (i < 8) cnt[i] = 0;
}

// K1: S1 = in-neighbors of mutation_idx (incl. self-loop), E2 = edge occurrences into mi
__global__ void k_scan1(const int* __restrict__ ei, const int* __restrict__ mip,
                        int* cnt, int* slot1, int* S1, int* E2){
  int e = blockIdx.x * 256 + threadIdx.x;
  if (e >= NE_TOT) return;
  int mi = mip[0];
  int src, dst;
  if (e < NE_RAW){ src = ei[e]; dst = ei[NE_RAW + e]; }
  else { src = e - NE_RAW; dst = src; }
  if (dst != mi) return;
  int p = atomicAdd(&cnt[3], 1);
  if (p < MAXE2) E2[p] = src;
  if (atomicCAS(&slot1[src], -1, -9) == -1){
    int idx = atomicAdd(&cnt[0], 1);
    if (idx < MAX1){ S1[idx] = src; slot1[src] = idx; }
  }
}

// K2: S2 = in-neighbors of S1; E1 = edge occurrences into S1
__global__ void k_scan2(const int* __restrict__ ei, int* cnt,
                        const int* __restrict__ slot1, int* slot2,
                        int* S2, int* E1s, int* E1d){
  int e = blockIdx.x * 256 + threadIdx.x;
  if (e >= NE_TOT) return;
  int src, dst;
  if (e < NE_RAW){ src = ei[e]; dst = ei[NE_RAW + e]; }
  else { src = e - NE_RAW; dst = src; }
  if (slot1[dst] < 0) return;
  int p = atomicAdd(&cnt[2], 1);
  if (p < MAXE1){ E1s[p] = src; E1d[p] = dst; }
  if (atomicCAS(&slot2[src], -1, -9) == -1){
    int idx = atomicAdd(&cnt[1], 1);
    if (idx < MAX2){ S2[idx] = src; slot2[src] = idx; }
  }
}

// K3: hh[i,:] = x[S2[i],:] @ W1  (pruned GEMM) ; last 4 blocks: r1 = relu(msd@Wm1+bm1)
__global__ __launch_bounds__(256) void k_hh(
    const float* __restrict__ x, const float* __restrict__ W1,
    const float* __restrict__ msd, const float* __restrict__ Wm1,
    const float* __restrict__ bm1,
    const int* __restrict__ cnt, const int* __restrict__ S2,
    float* __restrict__ hh, float* __restrict__ r1){
  int t = threadIdx.x;
  if (blockIdx.x >= K3_GEMM_BLOCKS){
    __shared__ float red[256];
    int b   = blockIdx.x - K3_GEMM_BLOCKS;   // 0..3 -> 32 cols each
    int col = b * 32 + (t & 31);
    int sl  = t >> 5;                        // 8 k-slices of 128
    float p = 0.f;
    for (int k = sl * 128; k < sl * 128 + 128; ++k)
      p += msd[k] * Wm1[k * C2 + col];
    red[t] = p;
    __syncthreads();
    if (t < 32){
      float s = 0.f;
      #pragma unroll
      for (int q = 0; q < 8; ++q) s += red[q * 32 + t];
      float v = s + bm1[col];
      r1[col] = v > 0.f ? v : 0.f;
    }
    return;
  }
  __shared__ float xs[4 * 640];
  int n2 = cnt[1]; if (n2 > MAX2) n2 = MAX2;
  int nRG = (n2 + 3) >> 2;
  int nT  = nRG * 8;   // 4 col-tiles x 2 k-chunks
  for (int task = blockIdx.x; task < nT; task += K3_GEMM_BLOCKS){
    int rg = task >> 3;
    int ct = (task >> 1) & 3;
    int kc = task & 1;
    int r0 = rg * 4;
    int nr = n2 - r0; if (nr > 4) nr = 4;
    int k0 = kc * 640;
    __syncthreads();
    for (int idx = t; idx < 4 * 640; idx += 256){
      int r = idx / 640, kk = idx - r * 640;
      float v = 0.f;
      if (r < nr) v = x[(long)S2[r0 + r] * FIN + k0 + kk];
      xs[idx] = v;
    }
    __syncthreads();
    int col = ct * 256 + t;
    float a0 = 0.f, a1 = 0.f, a2 = 0.f, a3 = 0.f;
    const float* Wp = W1 + (long)k0 * FH + col;
    #pragma unroll 4
    for (int kk = 0; kk < 640; ++kk){
      float w = Wp[(long)kk * FH];
      a0 += xs[kk]        * w;
      a1 += xs[640 + kk]  * w;
      a2 += xs[1280 + kk] * w;
      a3 += xs[1920 + kk] * w;
    }
    float* hp = hh + (long)r0 * FH + col;
    atomicAdd(hp, a0);
    if (nr > 1) atomicAdd(hp + FH,     a1);
    if (nr > 2) atomicAdd(hp + 2 * FH, a2);
    if (nr > 3) atomicAdd(hp + 3 * FH, a3);
  }
}

// K4: attention scalars a_src1/a_dst1 per S2 row per head
__global__ void k_ascal(const float* __restrict__ hh,
                        const float* __restrict__ as1, const float* __restrict__ ad1,
                        const int* __restrict__ cnt,
                        float* __restrict__ asrc1, float* __restrict__ adst1){
  __shared__ float red4[4];
  int t = threadIdx.x;
  int n2 = cnt[1]; if (n2 > MAX2) n2 = MAX2;
  for (int i = blockIdx.x; i < n2; i += gridDim.x){
    #pragma unroll
    for (int h = 0; h < NHEAD; ++h){
      float v  = hh[(long)i * FH + h * HC + t];
      float ss = blockSum(v * as1[h * HC + t], red4);
      float sd = blockSum(v * ad1[h * HC + t], red4);
      if (t == 0){ asrc1[i * NHEAD + h] = ss; adst1[i * NHEAD + h] = sd; }
    }
  }
}

// K5: layer-1 segment softmax + aggregation -> h1 (relu, +b1) for S1 nodes
__global__ void k_agg1(const float* __restrict__ hh,
                       const float* __restrict__ asrc1, const float* __restrict__ adst1,
                       const float* __restrict__ b1,
                       const int* __restrict__ cnt, const int* __restrict__ S1,
                       const int* __restrict__ slot2,
                       const int* __restrict__ E1s, const int* __restrict__ E1d,
                       float* __restrict__ h1){
  __shared__ int   lsrc[CAPE];
  __shared__ float ev[NHEAD][CAPE];
  __shared__ int   scnt;
  int t = threadIdx.x;
  int n1  = cnt[0]; if (n1  > MAX1)  n1  = MAX1;
  int nE1 = cnt[2]; if (nE1 > MAXE1) nE1 = MAXE1;
  for (int j = blockIdx.x; j < n1; j += gridDim.x){
    int s = S1[j];
    __syncthreads();
    if (t == 0) scnt = 0;
    __syncthreads();
    for (int e = t; e < nE1; e += 256){
      if (E1d[e] == s){
        int p = atomicAdd(&scnt, 1);
        if (p < CAPE) lsrc[p] = slot2[E1s[e]];
      }
    }
    __syncthreads();
    int ce = scnt; if (ce > CAPE) ce = CAPE;
    int w = t >> 6, lane = t & 63;
    int j2 = slot2[s];
    float ad = adst1[j2 * NHEAD + w];
    float m = -3.4e38f;
    for (int e = lane; e < ce; e += 64){
      float v = lrelu(asrc1[lsrc[e] * NHEAD + w] + ad);
      ev[w][e] = v;
      m = fmaxf(m, v);
    }
    #pragma unroll
    for (int o = 32; o; o >>= 1) m = fmaxf(m, __shfl_xor(m, o, 64));
    float ssum = 0.f;
    for (int e = lane; e < ce; e += 64){
      float a = expf(ev[w][e] - m);
      ev[w][e] = a;
      ssum += a;
    }
    #pragma unroll
    for (int o = 32; o; o >>= 1) ssum += __shfl_xor(ssum, o, 64);
    float inv = 1.f / (ssum + 1e-16f);
    for (int e = lane; e < ce; e += 64) ev[w][e] *= inv;
    __syncthreads();
    #pragma unroll
    for (int q = 0; q < 4; ++q){
      int c = q * 256 + t;     // head = q
      float acc = 0.f;
      for (int e = 0; e < ce; ++e)
        acc += ev[q][e] * hh[(long)lsrc[e] * FH + c];
      float v = acc + b1[c];
      h1[(long)j * FH + c] = v > 0.f ? v : 0.f;
    }
  }
}

// K6: g = h1@W2 per S1 node, plus layer-2 attention scalars
__global__ void k_g2(const float* __restrict__ h1, const float* __restrict__ W2,
                     const float* __restrict__ as2, const float* __restrict__ ad2,
                     const int* __restrict__ cnt,
                     float* __restrict__ gb, float* __restrict__ as2v,
                     float* __restrict__ ad2v){
  __shared__ float hs[FH];
  __shared__ float red[256];
  __shared__ float red4[4];
  int t = threadIdx.x;
  int n1 = cnt[0]; if (n1 > MAX1) n1 = MAX1;
  for (int j = blockIdx.x; j < n1; j += gridDim.x){
    __syncthreads();
    for (int idx = t; idx < FH; idx += 256) hs[idx] = h1[(long)j * FH + idx];
    __syncthreads();
    int col = t & 127, half = t >> 7;
    float p = 0.f;
    for (int k = half * 512; k < half * 512 + 512; ++k)
      p += hs[k] * W2[k * C2 + col];
    red[t] = p;
    __syncthreads();
    float gv = 0.f;
    if (t < 128){ gv = red[t] + red[t + 128]; gb[j * C2 + t] = gv; }
    float vs = (t < 128) ? gv * as2[t] : 0.f;
    float vd = (t < 128) ? gv * ad2[t] : 0.f;
    float s1 = blockSum(vs, red4);
    float s2 = blockSum(vd, red4);
    if (t == 0){ as2v[j] = s1; ad2v[j] = s2; }
  }
}

// K7: layer-2 softmax+aggregate at mi, then full MLP head -> scalar
__global__ void k_final(const int* __restrict__ mip, const int* __restrict__ cnt,
                        const int* __restrict__ slot1, const int* __restrict__ E2,
                        const float* __restrict__ gb,
                        const float* __restrict__ as2v, const float* __restrict__ ad2v,
                        const float* __restrict__ b2,
                        const float* __restrict__ r1,
                        const float* __restrict__ Wm2, const float* __restrict__ bm2,
                        const float* __restrict__ Wp1, const float* __restrict__ bp1,
                        const float* __restrict__ Wp2, const float* __restrict__ bp2,
                        const float* __restrict__ Wp3, const float* __restrict__ bp3,
                        float* __restrict__ out){
  __shared__ float al[MAXE2];
  __shared__ int   jl[MAXE2];
  __shared__ float feat[C2], r2s[C2], z1s[C2], z2s[32];
  int t = threadIdx.x;
  int mi  = mip[0];
  int jmi = slot1[mi];
  int ne2 = cnt[3]; if (ne2 > MAXE2) ne2 = MAXE2;
  if (t < 64){
    float adv = ad2v[jmi];
    float m = -3.4e38f;
    for (int k = t; k < ne2; k += 64){
      int j = slot1[E2[k]];
      jl[k] = j;
      float v = lrelu(as2v[j] + adv);
      al[k] = v;
      m = fmaxf(m, v);
    }
    #pragma unroll
    for (int o = 32; o; o >>= 1) m = fmaxf(m, __shfl_xor(m, o, 64));
    float s = 0.f;
    for (int k = t; k < ne2; k += 64){
      float a = expf(al[k] - m);
      al[k] = a;
      s += a;
    }
    #pragma unroll
    for (int o = 32; o; o >>= 1) s += __shfl_xor(s, o, 64);
    float inv = 1.f / (s + 1e-16f);
    for (int k = t; k < ne2; k += 64) al[k] *= inv;
  }
  __syncthreads();
  if (t < C2){
    float acc = 0.f;
    for (int k = 0; k < ne2; ++k) acc += al[k] * gb[jl[k] * C2 + t];
    float v = acc + b2[t];
    feat[t] = v > 0.f ? v : 0.f;          // relu(gat2 + b2) at mi
    float pr = 0.f;
    for (int k = 0; k < C2; ++k) pr += r1[k] * Wm2[k * C2 + t];
    r2s[t] = pr + bm2[t];                 // pmd (no relu after 2nd matmul)
  }
  __syncthreads();
  if (t < C2){
    float acc = 0.f;
    for (int k = 0; k < C2; ++k) acc += feat[k] * Wp1[k * C2 + t];
    for (int k = 0; k < C2; ++k) acc += r2s[k] * Wp1[(C2 + k) * C2 + t];
    float v = acc + bp1[t];
    z1s[t] = v > 0.f ? v : 0.f;
  }
  __syncthreads();
  if (t < 32){
    float acc = 0.f;
    for (int k = 0; k < C2; ++k) acc += z1s[k] * Wp2[k * 32 + t];
    float v = acc + bp2[t];
    z2s[t] = v > 0.f ? v : 0.f;
  }
  __syncthreads();
  if (t == 0){
    float acc = 0.f;
    for (int k = 0; k < 32; ++k) acc += z2s[k] * Wp3[k];
    out[0] = acc + bp3[0];
  }
}

extern "C" void kernel_launch(void* const* d_in, const int* in_sizes, int n_in,
                              void* d_out, int out_size, void* d_ws, size_t ws_size,
                              hipStream_t stream){
  const float* x   = (const float*)d_in[0];
  const int*   ei  = (const int*)d_in[1];
  const int*   mip = (const int*)d_in[2];
  const float* msd = (const float*)d_in[3];
  const float* Wm1 = (const float*)d_in[4];
  const float* bm1 = (const float*)d_in[5];
  const float* Wm2 = (const float*)d_in[6];
  const float* bm2 = (const float*)d_in[7];
  const float* W1  = (const float*)d_in[8];
  const float* as1 = (const float*)d_in[9];
  const float* ad1 = (const float*)d_in[10];
  const float* b1  = (const float*)d_in[11];
  const float* W2  = (const float*)d_in[12];
  const float* as2 = (const float*)d_in[13];
  const float* ad2 = (const float*)d_in[14];
  const float* b2  = (const float*)d_in[15];
  const float* Wp1 = (const float*)d_in[16];
  const float* bp1 = (const float*)d_in[17];
  const float* Wp2 = (const float*)d_in[18];
  const float* bp2 = (const float*)d_in[19];
  const float* Wp3 = (const float*)d_in[20];
  const float* bp3 = (const float*)d_in[21];
  float* out = (float*)d_out;

  char* p = (char*)d_ws;
  auto alloc = [&](size_t bytes) -> void* {
    void* r = (void*)p;
    p += (bytes + 255) & ~(size_t)255;
    return r;
  };
  int* cnt   = (int*)alloc(8 * 4);                       // n1, n2, nE1, nE2
  int* slot1 = (int*)alloc(NNODES * 4);
  int* slot2 = (int*)alloc(NNODES * 4);
  int* S1    = (int*)alloc(MAX1 * 4);
  int* S2    = (int*)alloc(MAX2 * 4);
  int* E1s   = (int*)alloc(MAXE1 * 4);
  int* E1d   = (int*)alloc(MAXE1 * 4);
  int* E2    = (int*)alloc(MAXE2 * 4);
  float* hh    = (float*)alloc((size_t)MAX2 * FH * 4);
  float* asrc1 = (float*)alloc(MAX2 * NHEAD * 4);
  float* adst1 = (float*)alloc(MAX2 * NHEAD * 4);
  float* h1    = (float*)alloc((size_t)MAX1 * FH * 4);
  float* gb    = (float*)alloc(MAX1 * C2 * 4);
  float* as2v  = (float*)alloc(MAX1 * 4);
  float* ad2v  = (float*)alloc(MAX1 * 4);
  float* r1    = (float*)alloc(C2 * 4);

  hipMemsetAsync(hh, 0, (size_t)MAX2 * FH * 4, stream);  // hh accumulated via atomics
  k_init<<<(NNODES + 255) / 256, 256, 0, stream>>>(cnt, slot1, slot2);
  k_scan1<<<(NE_TOT + 255) / 256, 256, 0, stream>>>(ei, mip, cnt, slot1, S1, E2);
  k_scan2<<<(NE_TOT + 255) / 256, 256, 0, stream>>>(ei, cnt, slot1, slot2, S2, E1s, E1d);
  k_hh<<<K3_GEMM_BLOCKS + 4, 256, 0, stream>>>(x, W1, msd, Wm1, bm1, cnt, S2, hh, r1);
  k_ascal<<<64, 256, 0, stream>>>(hh, as1, ad1, cnt, asrc1, adst1);
  k_agg1<<<64, 256, 0, stream>>>(hh, asrc1, adst1, b1, cnt, S1, slot2, E1s, E1d, h1);
  k_g2<<<64, 256, 0, stream>>>(h1, W2, as2, ad2, cnt, gb, as2v, ad2v);
  k_final<<<1, 256, 0, stream>>>(mip, cnt, slot1, E2, gb, as2v, ad2v, b2, r1,
                                 Wm2, bm2, Wp1, bp1, Wp2, bp2, Wp3, bp3, out);
}

// Round 2
// 61.576 us; speedup vs baseline: 2.1640x; 2.1640x over previous
//
#include <hip/hip_runtime.h>
#include <hip/hip_bf16.h>

#define NNODES 20000
#define NE_RAW 200000
#define NE_TOT 220000
#define MAX1   128
#define MAX2   512
#define MAXE1  4096
#define MAXE2  256
#define FIN    1280
#define FH     1024
#define HC     256
#define NHEAD  4
#define C2     128
#define CAPE   512
#define GB_HH  544     // k_hh gemm blocks (plus 4 pmd blocks)
#define GB_GB  128     // k_gb blocks

__device__ __forceinline__ float lrelu(float x){ return x >= 0.f ? x : 0.2f * x; }

__device__ __forceinline__ float blockSum(float v, float* red4){
  #pragma unroll
  for (int o = 32; o; o >>= 1) v += __shfl_xor(v, o, 64);
  int t = threadIdx.x;
  __syncthreads();
  if ((t & 63) == 0) red4[t >> 6] = v;
  __syncthreads();
  return red4[0] + red4[1] + red4[2] + red4[3];
}

// K0: reset slot maps + counters (hh/gb zeroed via hipMemsetAsync)
__global__ void k_init(int* cnt, int* slot1, int* slot2){
  int i = blockIdx.x * 256 + threadIdx.x;
  if (i < NNODES){ slot1[i] = -1; slot2[i] = -1; }
  if (i < 8) cnt[i] = 0;
}

// K1: S1 = in-neighbors of mutation_idx (incl. self-loop), E2 = edge occurrences into mi
__global__ void k_scan1(const int* __restrict__ ei, const int* __restrict__ mip,
                        int* cnt, int* slot1, int* S1, int* E2){
  int e = blockIdx.x * 256 + threadIdx.x;
  if (e >= NE_TOT) return;
  int mi = mip[0];
  int src, dst;
  if (e < NE_RAW){ src = ei[e]; dst = ei[NE_RAW + e]; }
  else { src = e - NE_RAW; dst = src; }
  if (dst != mi) return;
  int p = atomicAdd(&cnt[3], 1);
  if (p < MAXE2) E2[p] = src;
  if (atomicCAS(&slot1[src], -1, -9) == -1){
    int idx = atomicAdd(&cnt[0], 1);
    if (idx < MAX1){ S1[idx] = src; slot1[src] = idx; }
  }
}

// K2: S2 = in-neighbors of S1; E1 = edge occurrences into S1
__global__ void k_scan2(const int* __restrict__ ei, int* cnt,
                        const int* __restrict__ slot1, int* slot2,
                        int* S2, int* E1s, int* E1d){
  int e = blockIdx.x * 256 + threadIdx.x;
  if (e >= NE_TOT) return;
  int src, dst;
  if (e < NE_RAW){ src = ei[e]; dst = ei[NE_RAW + e]; }
  else { src = e - NE_RAW; dst = src; }
  if (slot1[dst] < 0) return;
  int p = atomicAdd(&cnt[2], 1);
  if (p < MAXE1){ E1s[p] = src; E1d[p] = dst; }
  if (atomicCAS(&slot2[src], -1, -9) == -1){
    int idx = atomicAdd(&cnt[1], 1);
    if (idx < MAX2){ S2[idx] = src; slot2[src] = idx; }
  }
}

// K3: hh[i,:] = x[S2[i],:] @ W1  (pruned GEMM, atomic accumulate over k-chunks)
//     last 4 blocks: r1 = relu(msd@Wm1+bm1)
__global__ __launch_bounds__(256) void k_hh(
    const float* __restrict__ x, const float* __restrict__ W1,
    const float* __restrict__ msd, const float* __restrict__ Wm1,
    const float* __restrict__ bm1,
    const int* __restrict__ cnt, const int* __restrict__ S2,
    float* __restrict__ hh, float* __restrict__ r1){
  int t = threadIdx.x;
  if (blockIdx.x >= GB_HH){
    __shared__ float red[256];
    int b   = blockIdx.x - GB_HH;            // 0..3 -> 32 cols each
    int col = b * 32 + (t & 31);
    int sl  = t >> 5;                        // 8 k-slices of 128
    float p = 0.f;
    for (int k = sl * 128; k < sl * 128 + 128; ++k)
      p += msd[k] * Wm1[k * C2 + col];
    red[t] = p;
    __syncthreads();
    if (t < 32){
      float s = 0.f;
      #pragma unroll
      for (int q = 0; q < 8; ++q) s += red[q * 32 + t];
      float v = s + bm1[col];
      r1[col] = v > 0.f ? v : 0.f;
    }
    return;
  }
  __shared__ float xs[8 * 160];
  int n2 = cnt[1]; if (n2 > MAX2) n2 = MAX2;
  int nRG = (n2 + 7) >> 3;
  int nT  = nRG * 32;                        // 4 col-tiles x 8 k-chunks of 160
  for (int task = blockIdx.x; task < nT; task += GB_HH){
    int rg  = task >> 5;
    int rem = task & 31;
    int ct  = rem >> 3;
    int kc  = rem & 7;
    int r0  = rg * 8;
    int nr  = n2 - r0; if (nr > 8) nr = 8;
    int k0  = kc * 160;
    __syncthreads();
    for (int idx = t; idx < 8 * 40; idx += 256){   // float4 staging
      int r = idx / 40, k4 = idx - r * 40;
      float4 v = make_float4(0.f, 0.f, 0.f, 0.f);
      if (r < nr)
        v = *(const float4*)(x + (long)S2[r0 + r] * FIN + k0 + k4 * 4);
      *(float4*)(xs + r * 160 + k4 * 4) = v;
    }
    __syncthreads();
    int col = ct * 256 + t;
    float acc[8] = {0.f,0.f,0.f,0.f,0.f,0.f,0.f,0.f};
    const float* Wp = W1 + (long)k0 * FH + col;
    #pragma unroll 4
    for (int kk = 0; kk < 160; ++kk){
      float w = Wp[(long)kk * FH];
      #pragma unroll
      for (int r = 0; r < 8; ++r) acc[r] += xs[r * 160 + kk] * w;
    }
    #pragma unroll
    for (int r = 0; r < 8; ++r)
      if (r < nr) atomicAdd(hh + (long)(r0 + r) * FH + col, acc[r]);
  }
}

// K4: attention scalars a_src1/a_dst1 per S2 row per head — wave-per-head, shfl-only
__global__ void k_ascal(const float* __restrict__ hh,
                        const float* __restrict__ as1, const float* __restrict__ ad1,
                        const int* __restrict__ cnt,
                        float* __restrict__ asrc1, float* __restrict__ adst1){
  int t = threadIdx.x, w = t >> 6, lane = t & 63;
  int n2 = cnt[1]; if (n2 > MAX2) n2 = MAX2;
  for (int i = blockIdx.x; i < n2; i += gridDim.x){
    const float* row = hh + (long)i * FH + w * HC;
    float ss = 0.f, sd = 0.f;
    #pragma unroll
    for (int q = 0; q < 4; ++q){
      float v = row[q * 64 + lane];
      ss += v * as1[w * HC + q * 64 + lane];
      sd += v * ad1[w * HC + q * 64 + lane];
    }
    #pragma unroll
    for (int o = 32; o; o >>= 1){
      ss += __shfl_xor(ss, o, 64);
      sd += __shfl_xor(sd, o, 64);
    }
    if (lane == 0){ asrc1[i * NHEAD + w] = ss; adst1[i * NHEAD + w] = sd; }
  }
}

// K5: layer-1 segment softmax + aggregation -> h1; one block per (node, head)
__global__ void k_agg1(const float* __restrict__ hh,
                       const float* __restrict__ asrc1, const float* __restrict__ adst1,
                       const float* __restrict__ b1,
                       const int* __restrict__ cnt, const int* __restrict__ S1,
                       const int* __restrict__ slot2,
                       const int* __restrict__ E1s, const int* __restrict__ E1d,
                       float* __restrict__ h1){
  __shared__ int   lsrc[CAPE];
  __shared__ float ev[CAPE];
  __shared__ int   scnt;
  int t = threadIdx.x;
  int n1  = cnt[0]; if (n1  > MAX1)  n1  = MAX1;
  int nE1 = cnt[2]; if (nE1 > MAXE1) nE1 = MAXE1;
  int nT = n1 * NHEAD;
  for (int task = blockIdx.x; task < nT; task += gridDim.x){
    int j = task >> 2, hd = task & 3;
    int s = S1[j];
    __syncthreads();
    if (t == 0) scnt = 0;
    __syncthreads();
    for (int e = t; e < nE1; e += 256){
      if (E1d[e] == s){
        int p = atomicAdd(&scnt, 1);
        if (p < CAPE) lsrc[p] = slot2[E1s[e]];
      }
    }
    __syncthreads();
    int ce = scnt; if (ce > CAPE) ce = CAPE;
    if (t < 64){
      float ad = adst1[slot2[s] * NHEAD + hd];
      float m = -3.4e38f;
      for (int e = t; e < ce; e += 64){
        float v = lrelu(asrc1[lsrc[e] * NHEAD + hd] + ad);
        ev[e] = v;
        m = fmaxf(m, v);
      }
      #pragma unroll
      for (int o = 32; o; o >>= 1) m = fmaxf(m, __shfl_xor(m, o, 64));
      float ssum = 0.f;
      for (int e = t; e < ce; e += 64){
        float a = expf(ev[e] - m);
        ev[e] = a;
        ssum += a;
      }
      #pragma unroll
      for (int o = 32; o; o >>= 1) ssum += __shfl_xor(ssum, o, 64);
      float inv = 1.f / (ssum + 1e-16f);
      for (int e = t; e < ce; e += 64) ev[e] *= inv;
    }
    __syncthreads();
    int c = hd * HC + t;
    float acc = 0.f;
    for (int e = 0; e < ce; ++e)
      acc += ev[e] * hh[(long)lsrc[e] * FH + c];
    float v = acc + b1[c];
    h1[(long)j * FH + c] = v > 0.f ? v : 0.f;
    __syncthreads();
  }
}

// K6: gb[j,:] += h1[j, k-chunk] @ W2[k-chunk, :]  (8 k-chunks per j, atomicAdd)
__global__ __launch_bounds__(256) void k_gb(
    const float* __restrict__ h1, const float* __restrict__ W2,
    const int* __restrict__ cnt, float* __restrict__ gb){
  __shared__ float hs[128];
  int t = threadIdx.x;
  int n1 = cnt[0]; if (n1 > MAX1) n1 = MAX1;
  int nT = n1 * 8;
  for (int task = blockIdx.x; task < nT; task += GB_GB){
    int j  = task >> 3;
    int kc = task & 7;
    int k0 = kc * 128;
    __syncthreads();
    if (t < 128) hs[t] = h1[(long)j * FH + k0 + t];
    __syncthreads();
    int col = t & 127, sub = t >> 7;
    const float* Wp = W2 + (long)(k0 + sub * 64) * C2 + col;
    const float* hp = hs + sub * 64;
    float acc = 0.f;
    #pragma unroll 16
    for (int i = 0; i < 64; ++i)
      acc += hp[i] * Wp[(long)i * C2];
    atomicAdd(gb + j * C2 + col, acc);
  }
}

// K7: layer-2 attention scalars + softmax + aggregate at mi, then MLP head -> scalar
__global__ void k_final(const int* __restrict__ mip, const int* __restrict__ cnt,
                        const int* __restrict__ slot1, const int* __restrict__ E2,
                        const float* __restrict__ gb,
                        const float* __restrict__ as2, const float* __restrict__ ad2,
                        const float* __restrict__ b2,
                        const float* __restrict__ r1,
                        const float* __restrict__ Wm2, const float* __restrict__ bm2,
                        const float* __restrict__ Wp1, const float* __restrict__ bp1,
                        const float* __restrict__ Wp2, const float* __restrict__ bp2,
                        const float* __restrict__ Wp3, const float* __restrict__ bp3,
                        float* __restrict__ out){
  __shared__ float al[MAXE2];
  __shared__ int   jl[MAXE2];
  __shared__ float red4[4];
  __shared__ float feat[C2], r2s[C2], z1s[C2], z2s[32];
  int t = threadIdx.x;
  int mi  = mip[0];
  int jmi = slot1[mi];
  int ne2 = cnt[3]; if (ne2 > MAXE2) ne2 = MAXE2;
  for (int k = t; k < ne2; k += 256) jl[k] = slot1[E2[k]];
  __syncthreads();
  // a_dst2 at mi
  float vd = (t < C2) ? gb[jmi * C2 + t] * ad2[t] : 0.f;
  float adv = blockSum(vd, red4);
  // per-edge a_src2 -> raw attention logits
  for (int k = 0; k < ne2; ++k){
    float vs = (t < C2) ? gb[jl[k] * C2 + t] * as2[t] : 0.f;
    float s = blockSum(vs, red4);
    if (t == 0) al[k] = lrelu(s + adv);
    __syncthreads();
  }
  if (t < 64){
    float m = -3.4e38f;
    for (int k = t; k < ne2; k += 64) m = fmaxf(m, al[k]);
    #pragma unroll
    for (int o = 32; o; o >>= 1) m = fmaxf(m, __shfl_xor(m, o, 64));
    float s = 0.f;
    for (int k = t; k < ne2; k += 64){
      float a = expf(al[k] - m);
      al[k] = a;
      s += a;
    }
    #pragma unroll
    for (int o = 32; o; o >>= 1) s += __shfl_xor(s, o, 64);
    float inv = 1.f / (s + 1e-16f);
    for (int k = t; k < ne2; k += 64) al[k] *= inv;
  }
  __syncthreads();
  if (t < C2){
    float acc = 0.f;
    for (int k = 0; k < ne2; ++k) acc += al[k] * gb[jl[k] * C2 + t];
    float v = acc + b2[t];
    feat[t] = v > 0.f ? v : 0.f;          // relu(gat2 + b2) at mi
    float pr = 0.f;
    for (int k = 0; k < C2; ++k) pr += r1[k] * Wm2[k * C2 + t];
    r2s[t] = pr + bm2[t];                 // pmd (no relu after 2nd matmul)
  }
  __syncthreads();
  if (t < C2){
    float acc = 0.f;
    for (int k = 0; k < C2; ++k) acc += feat[k] * Wp1[k * C2 + t];
    for (int k = 0; k < C2; ++k) acc += r2s[k] * Wp1[(C2 + k) * C2 + t];
    float v = acc + bp1[t];
    z1s[t] = v > 0.f ? v : 0.f;
  }
  __syncthreads();
  if (t < 32){
    float acc = 0.f;
    for (int k = 0; k < C2; ++k) acc += z1s[k] * Wp2[k * 32 + t];
    float v = acc + bp2[t];
    z2s[t] = v > 0.f ? v : 0.f;
  }
  __syncthreads();
  if (t == 0){
    float acc = 0.f;
    for (int k = 0; k < 32; ++k) acc += z2s[k] * Wp3[k];
    out[0] = acc + bp3[0];
  }
}

extern "C" void kernel_launch(void* const* d_in, const int* in_sizes, int n_in,
                              void* d_out, int out_size, void* d_ws, size_t ws_size,
                              hipStream_t stream){
  const float* x   = (const float*)d_in[0];
  const int*   ei  = (const int*)d_in[1];
  const int*   mip = (const int*)d_in[2];
  const float* msd = (const float*)d_in[3];
  const float* Wm1 = (const float*)d_in[4];
  const float* bm1 = (const float*)d_in[5];
  const float* Wm2 = (const float*)d_in[6];
  const float* bm2 = (const float*)d_in[7];
  const float* W1  = (const float*)d_in[8];
  const float* as1 = (const float*)d_in[9];
  const float* ad1 = (const float*)d_in[10];
  const float* b1  = (const float*)d_in[11];
  const float* W2  = (const float*)d_in[12];
  const float* as2 = (const float*)d_in[13];
  const float* ad2 = (const float*)d_in[14];
  const float* b2  = (const float*)d_in[15];
  const float* Wp1 = (const float*)d_in[16];
  const float* bp1 = (const float*)d_in[17];
  const float* Wp2 = (const float*)d_in[18];
  const float* bp2 = (const float*)d_in[19];
  const float* Wp3 = (const float*)d_in[20];
  const float* bp3 = (const float*)d_in[21];
  float* out = (float*)d_out;

  char* p = (char*)d_ws;
  auto alloc = [&](size_t bytes) -> void* {
    void* r = (void*)p;
    p += (bytes + 255) & ~(size_t)255;
    return r;
  };
  int* cnt   = (int*)alloc(8 * 4);                       // n1, n2, nE1, nE2
  int* slot1 = (int*)alloc(NNODES * 4);
  int* slot2 = (int*)alloc(NNODES * 4);
  int* S1    = (int*)alloc(MAX1 * 4);
  int* S2    = (int*)alloc(MAX2 * 4);
  int* E1s   = (int*)alloc(MAXE1 * 4);
  int* E1d   = (int*)alloc(MAXE1 * 4);
  int* E2    = (int*)alloc(MAXE2 * 4);
  float* hh    = (float*)alloc((size_t)MAX2 * FH * 4);   // 2 MB
  float* gb    = (float*)alloc(MAX1 * C2 * 4);           // 64 KB, adjacent to hh
  float* asrc1 = (float*)alloc(MAX2 * NHEAD * 4);
  float* adst1 = (float*)alloc(MAX2 * NHEAD * 4);
  float* h1    = (float*)alloc((size_t)MAX1 * FH * 4);
  float* r1    = (float*)alloc(C2 * 4);

  // hh and gb are accumulated via atomics -> zero both in one memset
  hipMemsetAsync(hh, 0, (size_t)MAX2 * FH * 4 + 256 + MAX1 * C2 * 4, stream);
  k_init<<<(NNODES + 255) / 256, 256, 0, stream>>>(cnt, slot1, slot2);
  k_scan1<<<(NE_TOT + 255) / 256, 256, 0, stream>>>(ei, mip, cnt, slot1, S1, E2);
  k_scan2<<<(NE_TOT + 255) / 256, 256, 0, stream>>>(ei, cnt, slot1, slot2, S2, E1s, E1d);
  k_hh<<<GB_HH + 4, 256, 0, stream>>>(x, W1, msd, Wm1, bm1, cnt, S2, hh, r1);
  k_ascal<<<160, 256, 0, stream>>>(hh, as1, ad1, cnt, asrc1, adst1);
  k_agg1<<<64, 256, 0, stream>>>(hh, asrc1, adst1, b1, cnt, S1, slot2, E1s, E1d, h1);
  k_gb<<<GB_GB, 256, 0, stream>>>(h1, W2, cnt, gb);
  k_final<<<1, 256, 0, stream>>>(mip, cnt, slot1, E2, gb, as2, ad2, b2, r1,
                                 Wm2, bm2, Wp1, bp1, Wp2, bp2, Wp3, bp3, out);
}